// Round 4
// baseline (135.991 us; speedup 1.0000x reference)
//
#include <hip/hip_runtime.h>
#include <math.h>

#define DIM   512
#define NP    64
#define TRB   64            // query rows per block (sim kernel)
#define BK    32            // k per chunk
#define NCH   16            // chunks (512/32)
#define TAU   1e-5f         // gap34 flag threshold (cosine units)
#define RFB   128           // refine blocks

// workspace layout (bytes)
#define WS_PTRAW 0          // float[512][64] raw transposed protos (131072)
#define WS_INV64 131072     // double[64]   (512)
#define WS_INVPF 131584     // float[64]    (256)
#define WS_CNT   131840     // int          (4)
#define WS_LIST  131968     // int[65536]   (262144)

// ---------------------------------------------------------------------------
// insert helpers (descending top-k with index tracking)
// ---------------------------------------------------------------------------
__device__ __forceinline__ void ins4f(float v, int idx, float& v0, float& v1,
                                      float& v2, float& v3, int& j0, int& j1,
                                      int& j2, int& j3) {
  const bool b0 = v > v0, b1 = v > v1, b2 = v > v2, b3 = v > v3;
  v3 = b2 ? v2 : (b3 ? v : v3);  j3 = b2 ? j2 : (b3 ? idx : j3);
  v2 = b1 ? v1 : (b2 ? v : v2);  j2 = b1 ? j1 : (b2 ? idx : j2);
  v1 = b0 ? v0 : (b1 ? v : v1);  j1 = b0 ? j0 : (b1 ? idx : j1);
  v0 = b0 ? v  : v0;             j0 = b0 ? idx : j0;
}

__device__ __forceinline__ void ins3d(double v, int idx, double& b0, double& b1,
                                      double& b2, int& k0, int& k1, int& k2) {
  const bool c0 = v > b0, c1 = v > b1, c2 = v > b2;
  b2 = c1 ? b1 : (c2 ? v : b2);  k2 = c1 ? k1 : (c2 ? idx : k2);
  b1 = c0 ? b0 : (c1 ? v : b1);  k1 = c0 ? k0 : (c1 ? idx : k1);
  b0 = c0 ? v  : b0;             k0 = c0 ? idx : k0;
}

// ---------------------------------------------------------------------------
// Kernel 1: raw-transpose protos -> ptw[k][p]; fp64 inverse norms; zero count.
// ---------------------------------------------------------------------------
__global__ __launch_bounds__(256) void prep_kernel(
    const float* __restrict__ protos, float* __restrict__ ptw,
    double* __restrict__ inv64, float* __restrict__ invpf,
    int* __restrict__ cnt) {
  if (blockIdx.x == 0 && threadIdx.x == 0) *cnt = 0;
  const int p = (blockIdx.x * 256 + threadIdx.x) >> 6;
  const int lane = threadIdx.x & 63;
  if (p >= NP) return;
  const float4* pr = (const float4*)(protos + (size_t)p * DIM);
  const float4 a = pr[lane * 2];
  const float4 b = pr[lane * 2 + 1];
  double ss = (double)a.x * a.x + (double)a.y * a.y + (double)a.z * a.z +
              (double)a.w * a.w + (double)b.x * b.x + (double)b.y * b.y +
              (double)b.z * b.z + (double)b.w * b.w;
#pragma unroll
  for (int m = 1; m < 64; m <<= 1) ss += __shfl_xor(ss, m);
  const double inv = 1.0 / fmax(sqrt(ss), 1e-12);
  if (lane == 0) { inv64[p] = inv; invpf[p] = (float)inv; }
  const float v[8] = {a.x, a.y, a.z, a.w, b.x, b.y, b.z, b.w};
#pragma unroll
  for (int e = 0; e < 8; ++e)
    ptw[(size_t)(lane * 8 + e) * NP + p] = v[e];
}

// ---------------------------------------------------------------------------
// Kernel 2: fused fp32 sim GEMM -> in-register top4 -> softmax -> gather.
// 256 threads = 4 waves, 64 rows/block, grid 1024 (4 blocks/CU).
// Thread tile: 4 rows x 4 protos. Double-buffered LDS, 1 barrier/chunk.
// A tile XOR-swizzled: Ast[k][row ^ ((k>>2)<<2)].
// ---------------------------------------------------------------------------
__global__ __launch_bounds__(256, 4) void sim_kernel(
    const float* __restrict__ query, const float* __restrict__ protos,
    const float* __restrict__ ptw, const float* __restrict__ invpf,
    float* __restrict__ out, int* __restrict__ cnt, int* __restrict__ list) {
  __shared__ float Ast[2][BK][64];    // [buf][k][row^swz]   16 KiB
  __shared__ float Bst[2][BK][NP];    // [buf][k][proto]     16 KiB
  __shared__ float qiS[TRB];
  __shared__ float4 wiS[TRB];

  const int t = threadIdx.x;
  const int row0 = blockIdx.x * TRB;
  const int tr = t >> 4;              // 0..15 -> rows tr*4..tr*4+3
  const int tp = t & 15;              // 0..15 -> protos tp*4..tp*4+3
  const int sr = t >> 3;              // A staging row (0..31), +32 second
  const int sc = t & 7;               // A staging float4-col (k/4 in chunk)
  const int bk = t >> 4;              // B staging k (0..15), +16 second
  const int bp = t & 15;              // B staging float4-col (proto/4)

  const float* aptr0 = query + (size_t)(row0 + sr) * DIM + sc * 4;
  const float* aptr1 = query + (size_t)(row0 + sr + 32) * DIM + sc * 4;
  const float* bptr0 = ptw + (size_t)bk * NP + bp * 4;
  const float* bptr1 = ptw + (size_t)(bk + 16) * NP + bp * 4;

  float acc[4][4] = {};
  float na0 = 0.f, na1 = 0.f;

  float4 ar0 = *(const float4*)aptr0;
  float4 ar1 = *(const float4*)aptr1;
  float4 br0 = *(const float4*)bptr0;
  float4 br1 = *(const float4*)bptr1;

  const int rsw0 = sr ^ (sc << 2);          // swz row for k-group sc
  const int rsw1 = (sr + 32) ^ (sc << 2);

  for (int ch = 0; ch < NCH; ++ch) {
    const int b = ch & 1;
    // stage regs -> LDS
    Ast[b][sc * 4 + 0][rsw0] = ar0.x;
    Ast[b][sc * 4 + 1][rsw0] = ar0.y;
    Ast[b][sc * 4 + 2][rsw0] = ar0.z;
    Ast[b][sc * 4 + 3][rsw0] = ar0.w;
    Ast[b][sc * 4 + 0][rsw1] = ar1.x;
    Ast[b][sc * 4 + 1][rsw1] = ar1.y;
    Ast[b][sc * 4 + 2][rsw1] = ar1.z;
    Ast[b][sc * 4 + 3][rsw1] = ar1.w;
    *(float4*)&Bst[b][bk][bp * 4] = br0;
    *(float4*)&Bst[b][bk + 16][bp * 4] = br1;
    na0 += ar0.x * ar0.x + ar0.y * ar0.y + ar0.z * ar0.z + ar0.w * ar0.w;
    na1 += ar1.x * ar1.x + ar1.y * ar1.y + ar1.z * ar1.z + ar1.w * ar1.w;
    __syncthreads();
    if (ch + 1 < NCH) {
      ar0 = *(const float4*)(aptr0 + (ch + 1) * BK);
      ar1 = *(const float4*)(aptr1 + (ch + 1) * BK);
      br0 = *(const float4*)(bptr0 + (size_t)(ch + 1) * BK * NP);
      br1 = *(const float4*)(bptr1 + (size_t)(ch + 1) * BK * NP);
    }
#pragma unroll 8
    for (int kk = 0; kk < BK; ++kk) {
      const int swz = (kk >> 2) << 2;
      const float4 a4 = *(const float4*)&Ast[b][kk][(tr * 4) ^ swz];
      const float4 b4 = *(const float4*)&Bst[b][kk][tp * 4];
      const float av[4] = {a4.x, a4.y, a4.z, a4.w};
      const float bv[4] = {b4.x, b4.y, b4.z, b4.w};
#pragma unroll
      for (int i = 0; i < 4; ++i)
#pragma unroll
        for (int j = 0; j < 4; ++j)
          acc[i][j] = fmaf(av[i], bv[j], acc[i][j]);
    }
  }

  // per-row 1/|q| : reduce sumsq across the 8 staging cols (consecutive lanes)
  na0 += __shfl_xor(na0, 1); na1 += __shfl_xor(na1, 1);
  na0 += __shfl_xor(na0, 2); na1 += __shfl_xor(na1, 2);
  na0 += __shfl_xor(na0, 4); na1 += __shfl_xor(na1, 4);
  if ((t & 7) == 0) {
    qiS[sr] = 1.0f / fmaxf(sqrtf(na0), 1e-12f);
    qiS[sr + 32] = 1.0f / fmaxf(sqrtf(na1), 1e-12f);
  }
  __syncthreads();

  // selection: per row, 16-lane shfl-merge of top-4 (value = dot * invp)
  const float4 ipv = *(const float4*)(invpf + tp * 4);
  const float ip[4] = {ipv.x, ipv.y, ipv.z, ipv.w};
#pragma unroll
  for (int i = 0; i < 4; ++i) {
    const int row = tr * 4 + i;
    float v0 = -1e30f, v1 = -1e30f, v2 = -1e30f, v3 = -1e30f;
    int j0 = 0, j1 = 0, j2 = 0, j3 = 0;
#pragma unroll
    for (int j = 0; j < 4; ++j)
      ins4f(acc[i][j] * ip[j], tp * 4 + j, v0, v1, v2, v3, j0, j1, j2, j3);
#pragma unroll
    for (int m = 1; m <= 8; m <<= 1) {
      const float p0 = __shfl_xor(v0, m), p1 = __shfl_xor(v1, m);
      const float p2 = __shfl_xor(v2, m), p3 = __shfl_xor(v3, m);
      const int q0 = __shfl_xor(j0, m), q1 = __shfl_xor(j1, m);
      const int q2 = __shfl_xor(j2, m), q3 = __shfl_xor(j3, m);
      ins4f(p0, q0, v0, v1, v2, v3, j0, j1, j2, j3);
      ins4f(p1, q1, v0, v1, v2, v3, j0, j1, j2, j3);
      ins4f(p2, q2, v0, v1, v2, v3, j0, j1, j2, j3);
      ins4f(p3, q3, v0, v1, v2, v3, j0, j1, j2, j3);
    }
    if (tp == 0) {
      const float qi = qiS[row];
      const float s0 = v0 * qi, s1 = v1 * qi, s2 = v2 * qi, s3 = v3 * qi;
      const float e1 = expf(s1 - s0), e2 = expf(s2 - s0);
      const float inv = 1.0f / (1.0f + e1 + e2);
      wiS[row] = make_float4(inv, e1 * inv, e2 * inv,
                             __int_as_float(j0 | (j1 << 6) | (j2 << 12)));
      if (s2 - s3 < TAU) {
        const int pos = atomicAdd(cnt, 1);
        list[pos] = row0 + row;
      }
    }
  }
  __syncthreads();

  // epilogue: (row, half) tasks, fully coalesced 1 KB stores
  const int wid = t >> 6;
  const int lane = t & 63;
#pragma unroll 4
  for (int it = 0; it < 32; ++it) {
    const int idx = it * 4 + wid;
    const int r = idx >> 1, h = idx & 1;
    const float4 wi = wiS[r];
    const int pack = __float_as_int(wi.w);
    const int i0 = pack & 63, i1 = (pack >> 6) & 63, i2 = (pack >> 12) & 63;
    const float4 pa = ((const float4*)(protos + (size_t)i0 * DIM + h * 256))[lane];
    const float4 pb = ((const float4*)(protos + (size_t)i1 * DIM + h * 256))[lane];
    const float4 pc = ((const float4*)(protos + (size_t)i2 * DIM + h * 256))[lane];
    float4 res;
    res.x = wi.x * pa.x + wi.y * pb.x + wi.z * pc.x;
    res.y = wi.x * pa.y + wi.y * pb.y + wi.z * pc.y;
    res.z = wi.x * pa.z + wi.y * pb.z + wi.z * pc.z;
    res.w = wi.x * pa.w + wi.y * pb.w + wi.z * pc.w;
    ((float4*)(out + (size_t)(row0 + r) * DIM + h * 256))[lane] = res;
  }
}

// ---------------------------------------------------------------------------
// Kernel 3: fp64 refine of compacted near-tie rows. One wave per row.
// ---------------------------------------------------------------------------
__global__ __launch_bounds__(256) void refine_kernel(
    const float* __restrict__ query, const float* __restrict__ protos,
    const float* __restrict__ ptw, const double* __restrict__ inv64,
    const int* __restrict__ cnt, const int* __restrict__ list,
    float* __restrict__ out) {
  const int n = *cnt;
  const int lane = threadIdx.x & 63;
  const int gw = blockIdx.x * 4 + (threadIdx.x >> 6);

  for (int i = gw; i < n; i += RFB * 4) {
    const int row = list[i];
    const float* q = query + (size_t)row * DIM;
    double a0 = 0.0, a1 = 0.0, a2 = 0.0, a3 = 0.0;
    float qs = 0.f;
#pragma unroll 4
    for (int k = 0; k < DIM; k += 4) {
      const float4 qv = *(const float4*)(q + k);
      a0 = fma((double)qv.x, (double)ptw[(size_t)(k + 0) * NP + lane], a0);
      a1 = fma((double)qv.y, (double)ptw[(size_t)(k + 1) * NP + lane], a1);
      a2 = fma((double)qv.z, (double)ptw[(size_t)(k + 2) * NP + lane], a2);
      a3 = fma((double)qv.w, (double)ptw[(size_t)(k + 3) * NP + lane], a3);
      qs += qv.x * qv.x + qv.y * qv.y + qv.z * qv.z + qv.w * qv.w;
    }
    const double sim = (a0 + a1 + a2 + a3) * inv64[lane];

    double b0 = sim, b1 = -1e300, b2 = -1e300;
    int k0 = lane, k1 = 0, k2 = 0;
#pragma unroll
    for (int m = 1; m <= 32; m <<= 1) {
      const double p0 = __shfl_xor(b0, m), p1 = __shfl_xor(b1, m),
                   p2 = __shfl_xor(b2, m);
      const int q0 = __shfl_xor(k0, m), q1 = __shfl_xor(k1, m),
                q2 = __shfl_xor(k2, m);
      ins3d(p0, q0, b0, b1, b2, k0, k1, k2);
      ins3d(p1, q1, b0, b1, b2, k0, k1, k2);
      ins3d(p2, q2, b0, b1, b2, k0, k1, k2);
    }
    const double qi = 1.0 / fmax(sqrt((double)qs), 1e-12);
    const double s0 = b0 * qi, s1 = b1 * qi, s2 = b2 * qi;
    const double e1 = exp(s1 - s0), e2 = exp(s2 - s0);
    const double inv = 1.0 / (1.0 + e1 + e2);
    const double w0 = inv, w1 = e1 * inv, w2 = e2 * inv;
    const float* p0r = protos + (size_t)k0 * DIM;
    const float* p1r = protos + (size_t)k1 * DIM;
    const float* p2r = protos + (size_t)k2 * DIM;
#pragma unroll
    for (int u = 0; u < 2; ++u) {
      const int col = u * 256 + lane * 4;
      const float4 x = *(const float4*)(p0r + col);
      const float4 y = *(const float4*)(p1r + col);
      const float4 z = *(const float4*)(p2r + col);
      float4 res;
      res.x = (float)(w0 * x.x + w1 * y.x + w2 * z.x);
      res.y = (float)(w0 * x.y + w1 * y.y + w2 * z.y);
      res.z = (float)(w0 * x.z + w1 * y.z + w2 * z.z);
      res.w = (float)(w0 * x.w + w1 * y.w + w2 * z.w);
      *(float4*)(out + (size_t)row * DIM + col) = res;
    }
  }
}

extern "C" void kernel_launch(void* const* d_in, const int* in_sizes, int n_in,
                              void* d_out, int out_size, void* d_ws, size_t ws_size,
                              hipStream_t stream) {
  const float* query = (const float*)d_in[0];
  const float* protos = (const float*)d_in[1];
  float* out = (float*)d_out;
  float* ptw = (float*)((char*)d_ws + WS_PTRAW);
  double* inv64 = (double*)((char*)d_ws + WS_INV64);
  float* invpf = (float*)((char*)d_ws + WS_INVPF);
  int* cnt = (int*)((char*)d_ws + WS_CNT);
  int* list = (int*)((char*)d_ws + WS_LIST);

  const int nrows = in_sizes[0] / DIM;

  hipLaunchKernelGGL(prep_kernel, dim3(16), dim3(256), 0, stream,
                     protos, ptw, inv64, invpf, cnt);
  hipLaunchKernelGGL(sim_kernel, dim3(nrows / TRB), dim3(256), 0, stream,
                     query, protos, ptw, invpf, out, cnt, list);
  hipLaunchKernelGGL(refine_kernel, dim3(RFB), dim3(256), 0, stream,
                     query, protos, ptw, inv64, cnt, list, out);
}